// Round 16
// baseline (333.065 us; speedup 1.0000x reference)
//
#include <hip/hip_runtime.h>
#include <stdint.h>

#define NN 1024
#define FF 35
#define LIN_IN 1610
#define NB 16

typedef short short8 __attribute__((ext_vector_type(8)));
typedef float f32x4 __attribute__((ext_vector_type(4)));
typedef float f32x2 __attribute__((ext_vector_type(2)));

__device__ __forceinline__ float leakyf(float x) { return fmaxf(x, 0.01f * x); }
__device__ __forceinline__ uint16_t to_bf16(float v) {
    return (uint16_t)((__float_as_uint(v) + 0x8000u) >> 16);
}
__device__ __forceinline__ f32x2 sp2(float s) { return (f32x2){s, s}; }
__device__ __forceinline__ f32x2 leaky2(f32x2 v) {
    f32x2 r;
    r.x = fmaxf(v.x, 0.01f * v.x);
    r.y = fmaxf(v.y, 0.01f * v.y);
    return r;
}
// orderable-uint mapping for float max via integer atomicMax (no NaNs in data)
__device__ __forceinline__ uint32_t mapf(float x) {
    uint32_t u = __float_as_uint(x);
    return (u & 0x80000000u) ? ~u : (u | 0x80000000u);
}
__device__ __forceinline__ float unmapf(uint32_t u) {
    return (u & 0x80000000u) ? __uint_as_float(u & 0x7FFFFFFFu) : __uint_as_float(~u);
}

// ---------------------------------------------------------------- prep: codes (s->u8) + labels->XT0/XR0 in one launch
__global__ __launch_bounds__(256)
void prep_kernel(const float* __restrict__ s, uint8_t* __restrict__ codes, int n4,
                 const float* __restrict__ labels, uint16_t* __restrict__ XT0,
                 float* __restrict__ XR0)
{
    const int bid = blockIdx.x;
    if (bid < 2048) {
        int i = bid * 256 + threadIdx.x;
        for (; i < n4; i += 2048 * 256) {
            float4 v = ((const float4*)s)[i];
            uchar4 c;
            c.x = (uint8_t)v.x; c.y = (uint8_t)v.y; c.z = (uint8_t)v.z; c.w = (uint8_t)v.w;
            ((uchar4*)codes)[i] = c;
        }
    } else {
        __shared__ float buf[256 * FF];
        const int lb = bid - 2048;
        const int si = lb >> 2;
        const int i0 = (lb & 3) * 256;
        const float* src = labels + ((size_t)si * NN + i0) * FF;
        for (int t = threadIdx.x; t < 256 * FF; t += 256) buf[t] = src[t];
        __syncthreads();
        for (int f = 0; f < 48; ++f) {
            const int ii = threadIdx.x;
            float v = (f < FF) ? buf[ii * FF + f] : 0.f;
            size_t o = ((size_t)si * 48 + f) * 1024 + i0 + ii;
            XR0[o] = v;
            XT0[o] = to_bf16(v);
        }
    }
}

// ---------------------------------------------------------------- one-hot A-fragment expansion
__device__ __forceinline__ short8 expand_onehot(uint2 cd, uint32_t dupK) {
    union { uint32_t u[4]; short8 v; } r;
#pragma unroll
    for (int h = 0; h < 2; ++h) {
        uint32_t d = h ? cd.y : cd.x;
        uint32_t y = d ^ dupK;
        uint32_t m = (~(((y & 0x7F7F7F7Fu) + 0x7F7F7F7Fu) | y)) & 0x80808080u;
        uint32_t m2 = m >> 7;                               // 0x01 at matched bytes
        r.u[h * 2 + 0] = ((m2 & 0xFFu) | ((m2 & 0xFF00u) << 8)) * 0x3F80u;
        r.u[h * 2 + 1] = (((m2 >> 16) & 0xFFu) | ((m2 >> 8) & 0xFF0000u)) * 0x3F80u;
    }
    return r.v;
}

// ---------------------------------------------------------------- WLC step body, LDS-staged both operands (r15 proven)
__device__ __forceinline__
void wlc_body(int mt, int nt, int s,
              const uint16_t* __restrict__ XT_in, const float* __restrict__ XR_in,
              uint16_t* __restrict__ XT_out, float* __restrict__ XR_out,
              const uint8_t* __restrict__ codes, const float* __restrict__ Kg,
              int t, int shift, int nch_in, int nch_out, int do_leaky)
{
    __shared__ __align__(16) uint16_t xs[48 * 64];   // B tile, XOR swizzle
    __shared__ __align__(16) uint8_t  cds[64 * 80];  // codes tile, 80B row stride

    const int tid   = threadIdx.x;
    const int wid   = tid >> 6;
    const int lane  = tid & 63;
    const int chout = nt;
    const int inch  = chout >> shift;
    const int kch   = chout & 1;
    const int i0    = mt * 64;
    const int irow0 = i0 + wid * 16;

    // B staging: 48 rows x 64 bf16 = 384 16B-units
    const int u0 = tid, u1 = tid + 256;
    const bool v1 = (u1 < 384);
    const int r0s = u0 >> 3, c80 = u0 & 7;
    const int r1s = u1 >> 3, c81 = u1 & 7;
    const uint16_t* src0 = XT_in + (((size_t)s * nch_in + inch) * 48 + r0s) * 1024 + c80 * 8;
    const uint16_t* src1 = XT_in + (((size_t)s * nch_in + inch) * 48 + (v1 ? r1s : 0)) * 1024 + c81 * 8;
    uint16_t* dst0 = &xs[r0s * 64 + ((c80 ^ (r0s & 7)) * 8)];
    uint16_t* dst1 = &xs[(v1 ? r1s : 0) * 64 + ((c81 ^ (r1s & 7)) * 8)];

    // codes staging: 64 rows x 64 B; thread t -> row t>>2, bytes (t&3)*16
    const int crow = tid >> 2, ccol = (tid & 3) * 16;
    const uint8_t* csrc = codes + ((size_t)s << 20) + (size_t)(i0 + crow) * 1024 + ccol;
    uint8_t* cdst = &cds[crow * 80 + ccol];

    const int cd_off = (wid * 16 + (lane & 15)) * 80 + ((lane >> 4) << 3);

    f32x4 acc[4][3];
#pragma unroll
    for (int k = 0; k < 4; ++k)
#pragma unroll
        for (int nf = 0; nf < 3; ++nf) acc[k][nf] = (f32x4){0.f, 0.f, 0.f, 0.f};

    uint4 preB0 = *(const uint4*)src0;
    uint4 preB1 = v1 ? *(const uint4*)src1 : (uint4){0, 0, 0, 0};
    uint4 preC  = *(const uint4*)csrc;

    for (int jt = 0; jt < 16; ++jt) {
        __syncthreads();                  // prev tile's LDS reads done
        *(uint4*)dst0 = preB0;
        if (v1) *(uint4*)dst1 = preB1;
        *(uint4*)cdst = preC;
        __syncthreads();

        if (jt < 15) {                    // prefetch next tile during compute
            const int j1 = (jt + 1) * 64;
            preB0 = *(const uint4*)(src0 + j1);
            if (v1) preB1 = *(const uint4*)(src1 + j1);
            preC  = *(const uint4*)(csrc + j1);
        }

        const uint2 cd0 = *(const uint2*)&cds[cd_off];
        const uint2 cd1 = *(const uint2*)&cds[cd_off + 32];

        short8 bfr[3][2];
#pragma unroll
        for (int nf = 0; nf < 3; ++nf)
#pragma unroll
            for (int kk = 0; kk < 2; ++kk) {
                int n = nf * 16 + (lane & 15);
                int c8 = kk * 4 + (lane >> 4);
                bfr[nf][kk] = *(const short8*)&xs[n * 64 + ((c8 ^ (n & 7)) * 8)];
            }

#pragma unroll
        for (int k = 0; k < 4; ++k) {
            const uint32_t dupK = 0x01010101u * (k + 1);
#pragma unroll
            for (int kk = 0; kk < 2; ++kk) {
                short8 af = expand_onehot(kk ? cd1 : cd0, dupK);
#pragma unroll
                for (int nf = 0; nf < 3; ++nf)
                    acc[k][nf] = __builtin_amdgcn_mfma_f32_16x16x32_bf16(
                        af, bfr[nf][kk], acc[k][nf], 0, 0, 0);
            }
        }
    }

    float sc[4][3];
#pragma unroll
    for (int nf = 0; nf < 3; ++nf) {
        int fnl = nf * 16 + (lane & 15);
#pragma unroll
        for (int k = 0; k < 4; ++k)
            sc[k][nf] = (fnl < FF) ? Kg[((kch * 2 + t) * 4 + k) * FF + fnl] : 0.f;
    }

#pragma unroll
    for (int nf = 0; nf < 3; ++nf) {
        int fnl = nf * 16 + (lane & 15);
        int irow = irow0 + ((lane >> 4) << 2);
        f32x4 rr = sc[0][nf] * acc[0][nf];
        rr += sc[1][nf] * acc[1][nf];
        rr += sc[2][nf] * acc[2][nf];
        rr += sc[3][nf] * acc[3][nf];
        size_t rb = (((size_t)s * nch_in + inch) * 48 + fnl) * 1024 + irow;
        float4 rd = *(const float4*)&XR_in[rb];
        float y0 = rr.x + rd.x, y1 = rr.y + rd.y, y2 = rr.z + rd.z, y3 = rr.w + rd.w;
        if (do_leaky) { y0 = leakyf(y0); y1 = leakyf(y1); y2 = leakyf(y2); y3 = leakyf(y3); }
        size_t ob = (((size_t)s * nch_out + chout) * 48 + fnl) * 1024 + irow;
        *(float4*)&XR_out[ob] = make_float4(y0, y1, y2, y3);
        ushort4 bv;
        bv.x = to_bf16(y0); bv.y = to_bf16(y1); bv.z = to_bf16(y2); bv.w = to_bf16(y3);
        *(ushort4*)&XT_out[ob] = bv;
    }
}

__global__ __launch_bounds__(256, 2)
void wlc_gemm(const uint16_t* __restrict__ XT_in, const float* __restrict__ XR_in,
              uint16_t* __restrict__ XT_out, float* __restrict__ XR_out,
              const uint8_t* __restrict__ codes, const float* __restrict__ Kg,
              int t, int shift, int nch_in, int nch_out, int do_leaky)
{
    wlc_body(blockIdx.x, blockIdx.y, blockIdx.z, XT_in, XR_in, XT_out, XR_out,
             codes, Kg, t, shift, nch_in, nch_out, do_leaky);
}

// ---------------------------------------------------------------- conv half-strip body: packed-f32, NR z2 rows (9 or 8)
// Finer scheduling grain: 17-row strip split into rh0 (z2 rows 0..8) and
// rh1 (rows 9..16). Full 1020-col width per block (255 threads x 4 cols).
// Pool bins (340/510/680 row boundaries) depend only on ss -> unchanged.
template<int NR>
__device__ __forceinline__
void conv_half(int ss, int rh, int simg,
               const float* __restrict__ sM,
               const float* __restrict__ cw1, const float* __restrict__ cb1,
               const float* __restrict__ cw2, const float* __restrict__ cb2,
               float* __restrict__ h0)
{
    __shared__ float bins[30];
    const int tid   = threadIdx.x;
    const int lane  = tid & 63;
    const int rbase = ss * 17 + rh * 9;
    const int rb2   = ss / 30;
    const int rb3   = ss / 20;

    if (tid < 30) bins[tid] = 0.f;
    __syncthreads();

    const int colbase = (tid < 255) ? tid * 4 : 254 * 4;
    const float* sp = sM + (size_t)simg * (NN * NN) + colbase;

    f32x2 w1p[9], w2p[45], b1p;
#pragma unroll
    for (int i = 0; i < 9; ++i) { w1p[i].x = cw1[i]; w1p[i].y = cw1[9 + i]; }
#pragma unroll
    for (int o = 0; o < 5; ++o)
#pragma unroll
        for (int i = 0; i < 9; ++i) {
            w2p[o * 9 + i].x = cw2[(o * 2 + 0) * 9 + i];
            w2p[o * 9 + i].y = cw2[(o * 2 + 1) * 9 + i];
        }
    b1p.x = cb1[0]; b1p.y = cb1[1];
    float b2r[5];
#pragma unroll
    for (int i = 0; i < 5; ++i) b2r[i] = cb2[i];

    float sw[3][8];
    f32x2 z1w[3][6];
    float acc[5][4];
#pragma unroll
    for (int o = 0; o < 5; ++o)
#pragma unroll
        for (int j = 0; j < 4; ++j) acc[o][j] = 0.f;

#define LOADROW(slot, rabs) do { \
    float4 v0 = *(const float4*)(sp + (size_t)(rabs) * NN); \
    float4 v1 = *(const float4*)(sp + (size_t)(rabs) * NN + 4); \
    sw[slot][0]=v0.x; sw[slot][1]=v0.y; sw[slot][2]=v0.z; sw[slot][3]=v0.w; \
    sw[slot][4]=v1.x; sw[slot][5]=v1.y; sw[slot][6]=v1.z; sw[slot][7]=v1.w; } while(0)

#define Z1ROW(P) do { \
    _Pragma("unroll") for (int jj = 0; jj < 6; ++jj) { \
        f32x2 a = b1p; \
        _Pragma("unroll") for (int dc = 0; dc < 3; ++dc) { \
            a += sp2(sw[((P)+2)%3][jj+dc]) * w1p[0+dc]; \
            a += sp2(sw[(P)%3    ][jj+dc]) * w1p[3+dc]; \
            a += sp2(sw[((P)+1)%3][jj+dc]) * w1p[6+dc]; } \
        z1w[((P)+2)%3][jj] = leaky2(a); } } while(0)

#define Z2ROW(P) do { \
    _Pragma("unroll") for (int o = 0; o < 5; ++o) { \
      _Pragma("unroll") for (int j = 0; j < 4; ++j) { \
        f32x2 a = (f32x2){b2r[o], 0.f}; \
        _Pragma("unroll") for (int dc = 0; dc < 3; ++dc) { \
            a += z1w[(P)%3    ][j+dc] * w2p[o*9+0+dc]; \
            a += z1w[((P)+1)%3][j+dc] * w2p[o*9+3+dc]; \
            a += z1w[((P)+2)%3][j+dc] * w2p[o*9+6+dc]; } \
        float sres = a.x + a.y; \
        acc[o][j] += fmaxf(sres, 0.01f * sres); } } } while(0)

#define STEPX(P, t) do { \
    LOADROW(((P)+1)%3, rbase + (t) + 4); \
    Z1ROW(P); \
    Z2ROW(P); } while(0)

    // prologue: s rows rbase..rbase+3, z1 local rows 0,1
    LOADROW(0, rbase + 0);
    LOADROW(1, rbase + 1);
    LOADROW(2, rbase + 2);
    Z1ROW(1);                 // z1 local row 0 -> slot 0
    LOADROW(0, rbase + 3);
    Z1ROW(2);                 // z1 local row 1 -> slot 1

    if (NR == 9) {
        STEPX(0, 0); STEPX(1, 1); STEPX(2, 2);
        STEPX(0, 3); STEPX(1, 4); STEPX(2, 5);
        STEPX(0, 6); STEPX(1, 7); STEPX(2, 8);
    } else {                  // NR == 8
        STEPX(0, 0); STEPX(1, 1); STEPX(2, 2);
        STEPX(0, 3); STEPX(1, 4); STEPX(2, 5);
        STEPX(0, 6); STEPX(1, 7);
    }

#undef LOADROW
#undef Z1ROW
#undef Z2ROW
#undef STEPX

    if (tid == 255) {
#pragma unroll
        for (int o = 0; o < 5; ++o)
#pragma unroll
            for (int j = 0; j < 4; ++j) acc[o][j] = 0.f;
    }

    int cb2c[4], cb3c[4];
#pragma unroll
    for (int j = 0; j < 4; ++j) {
        int col = colbase + j;
        int a2 = col / 510; if (a2 > 1) a2 = 1;
        int a3 = col / 340; if (a3 > 2) a3 = 2;
        cb2c[j] = a2; cb3c[j] = a3;
    }

#pragma unroll
    for (int o = 0; o < 5; ++o) {
        float t1 = acc[o][0] + acc[o][1] + acc[o][2] + acc[o][3];
        float pa = 0.f, pb = 0.f, q0 = 0.f, q1 = 0.f, q2 = 0.f;
#pragma unroll
        for (int j = 0; j < 4; ++j) {
            float v = acc[o][j];
            if (cb2c[j] == 0) pa += v; else pb += v;
            if (cb3c[j] == 0) q0 += v; else if (cb3c[j] == 1) q1 += v; else q2 += v;
        }
#pragma unroll
        for (int d = 32; d >= 1; d >>= 1) {
            t1 += __shfl_xor(t1, d, 64);
            pa += __shfl_xor(pa, d, 64);
            pb += __shfl_xor(pb, d, 64);
            q0 += __shfl_xor(q0, d, 64);
            q1 += __shfl_xor(q1, d, 64);
            q2 += __shfl_xor(q2, d, 64);
        }
        if (lane == 0) {
            atomicAdd(&bins[o * 6 + 0], t1);
            atomicAdd(&bins[o * 6 + 1], pa);
            atomicAdd(&bins[o * 6 + 2], pb);
            atomicAdd(&bins[o * 6 + 3], q0);
            atomicAdd(&bins[o * 6 + 4], q1);
            atomicAdd(&bins[o * 6 + 5], q2);
        }
    }
    __syncthreads();
    if (tid < 30) {
        int o = tid / 6, b = tid % 6;
        int off; float scale;
        if (b == 0)      { off = 0;                         scale = 1.f / (1020.f * 1020.f); }
        else if (b <= 2) { off = 1 + rb2 * 2 + (b - 1);     scale = 1.f / (510.f * 510.f); }
        else             { off = 5 + rb3 * 3 + (b - 3);     scale = 1.f / (340.f * 340.f); }
        atomicAdd(h0 + (size_t)simg * LIN_IN + 1540 + o * 14 + off, bins[tid] * scale);
    }
}

// ---------------------------------------------------------------- fused: conv half-strips + wlc stage blocks
__global__ __launch_bounds__(256, 2)
void fused_wlc_conv(int convBlocks, int convBase,
                    const float* __restrict__ sM,
                    const float* __restrict__ cw1, const float* __restrict__ cb1,
                    const float* __restrict__ cw2, const float* __restrict__ cb2,
                    float* __restrict__ h0,
                    const uint16_t* __restrict__ XT_in, const float* __restrict__ XR_in,
                    uint16_t* __restrict__ XT_out, float* __restrict__ XR_out,
                    const uint8_t* __restrict__ codes, const float* __restrict__ Kg,
                    int t, int shift, int nch_in, int nch_out, int do_leaky)
{
    const int bid = blockIdx.x;
    if (bid < convBlocks) {
        const int g = convBase + bid;
        const int ss = g % 60;
        const int rh = (g / 60) & 1;
        const int simg = g / 120;
        if (rh == 0)
            conv_half<9>(ss, 0, simg, sM, cw1, cb1, cw2, cb2, h0);
        else
            conv_half<8>(ss, 1, simg, sM, cw1, cb1, cw2, cb2, h0);
    } else {
        const int w = bid - convBlocks;
        wlc_body(w & 15, (w >> 4) & 3, w >> 6, XT_in, XR_in, XT_out, XR_out,
                 codes, Kg, t, shift, nch_in, nch_out, do_leaky);
    }
}

// ---------------------------------------------------------------- spp max: one block per (img,ch), scatter + inline unmap
__global__ __launch_bounds__(1024)
void spp_kernel(const float* __restrict__ xr4, float* __restrict__ h0)
{
    constexpr int KH[10] = {1024, 512, 342, 256, 205, 171, 147, 128, 114, 103};
    constexpr int PH[10] = {0, 0, 2, 0, 1, 2, 5, 0, 2, 6};
    constexpr int KW[10] = {35, 18, 12, 9, 7, 6, 5, 5, 4, 4};
    constexpr int PW[10] = {0, 1, 1, 1, 0, 1, 0, 2, 1, 2};
    constexpr int OW[10] = {1, 2, 3, 4, 5, 6, 7, 7, 9, 9};
    constexpr int OHW[10] = {1, 4, 9, 16, 25, 36, 49, 56, 81, 90};
    constexpr int BASE[10] = {0, 1, 5, 14, 30, 55, 91, 140, 204, 285};

    __shared__ uint32_t cells[385];
    const int c = blockIdx.x & 3;
    const int s = blockIdx.x >> 2;
    const int r = threadIdx.x;           // one row per thread

    if (r < 385) cells[r] = 0u;
    __syncthreads();

    const float* bp = xr4 + ((size_t)s * 4 + c) * (48 * 1024) + r;

    int addr[10];
#pragma unroll
    for (int pi = 0; pi < 10; ++pi)
        addr[pi] = BASE[pi] + ((r + PH[pi]) / KH[pi]) * OW[pi];

    float acc[10];
#pragma unroll
    for (int pi = 0; pi < 10; ++pi) acc[pi] = -3.402823466e38f;

#pragma unroll
    for (int f = 0; f < FF; ++f) {
        const float v = bp[(size_t)f * 1024];
#pragma unroll
        for (int pi = 0; pi < 10; ++pi) {
            const int cbin = (f + PW[pi]) / KW[pi];                    // compile-time
            const int cbn  = (f + 1 < FF) ? ((f + 1 + PW[pi]) / KW[pi]) : -1;
            if (cbin < OW[pi]) {
                acc[pi] = fmaxf(acc[pi], v);
                if (cbn != cbin) {                                     // static flush site
                    atomicMax(&cells[addr[pi] + cbin], mapf(acc[pi]));
                    acc[pi] = -3.402823466e38f;
                }
            }
        }
    }

    __syncthreads();
    if (r < 385) {
        int p1 = 1, base = 0;
        while (p1 < 10 && r >= base + p1 * p1) { base += p1 * p1; ++p1; }
        const int ci = r - base;
        const float val = (ci < OHW[p1 - 1]) ? unmapf(cells[r]) : 0.f;
        h0[(size_t)s * LIN_IN + c * 385 + r] = val;
    }
}

// ---------------------------------------------------------------- FC: 1 output/wave, vectorized unguarded main + tail
template<int VEC>
__global__ __launch_bounds__(256)
void fc_kernel(const float* __restrict__ in, const float* __restrict__ W,
               const float* __restrict__ bias, float* __restrict__ out,
               int K, int Nout, int do_leaky)
{
    const int o = (blockIdx.x * 256 + threadIdx.x) >> 6;
    const int lane = threadIdx.x & 63;
    if (o >= Nout) return;
    const float* wrow = W + (size_t)o * K;
    float acc[16];
#pragma unroll
    for (int b = 0; b < 16; ++b) acc[b] = 0.f;

    const int step = 64 * VEC;
    const int kmain = (K / step) * step;
#pragma unroll 2
    for (int k0 = 0; k0 < kmain; k0 += step) {
        const int kk = k0 + lane * VEC;
        if (VEC == 4) {
            float4 w = *(const float4*)(wrow + kk);
#pragma unroll
            for (int b = 0; b < 16; ++b) {
                float4 h = *(const float4*)(in + (size_t)b * K + kk);
                acc[b] += w.x * h.x + w.y * h.y + w.z * h.z + w.w * h.w;
            }
        } else {
            float2 w = *(const float2*)(wrow + kk);
#pragma unroll
            for (int b = 0; b < 16; ++b) {
                float2 h = *(const float2*)(in + (size_t)b * K + kk);
                acc[b] += w.x * h.x + w.y * h.y;
            }
        }
    }
    {
        const int kk = kmain + lane * VEC;
        if (kk < K) {
            if (VEC == 4) {
                float4 w = *(const float4*)(wrow + kk);
#pragma unroll
                for (int b = 0; b < 16; ++b) {
                    float4 h = *(const float4*)(in + (size_t)b * K + kk);
                    acc[b] += w.x * h.x + w.y * h.y + w.z * h.z + w.w * h.w;
                }
            } else {
                float2 w = *(const float2*)(wrow + kk);
#pragma unroll
                for (int b = 0; b < 16; ++b) {
                    float2 h = *(const float2*)(in + (size_t)b * K + kk);
                    acc[b] += w.x * h.x + w.y * h.y;
                }
            }
        }
    }

    float res = 0.f;
#pragma unroll
    for (int b = 0; b < 16; ++b) {
        float v = acc[b];
#pragma unroll
        for (int od = 32; od >= 1; od >>= 1) v += __shfl_xor(v, od, 64);
        if (lane == b) res = v;
    }
    if (lane < 16) {
        const float y = res + bias[o];
        out[(size_t)lane * Nout + o] = do_leaky ? leakyf(y) : y;
    }
}

// ---------------------------------------------------------------- launch
extern "C" void kernel_launch(void* const* d_in, const int* in_sizes, int n_in,
                              void* d_out, int out_size, void* d_ws, size_t ws_size,
                              hipStream_t stream)
{
    const float* labels = (const float*)d_in[0];
    const float* sM     = (const float*)d_in[1];
    const float* K1     = (const float*)d_in[2];
    const float* K2     = (const float*)d_in[3];
    const float* cw1    = (const float*)d_in[4];
    const float* cb1    = (const float*)d_in[5];
    const float* cw2    = (const float*)d_in[6];
    const float* cb2    = (const float*)d_in[7];
    const float* W1     = (const float*)d_in[8];
    const float* b1     = (const float*)d_in[9];
    const float* W2     = (const float*)d_in[10];
    const float* b2     = (const float*)d_in[11];
    const float* W3     = (const float*)d_in[12];
    const float* b3     = (const float*)d_in[13];
    const float* W4     = (const float*)d_in[14];
    const float* b4     = (const float*)d_in[15];
    const float* W5     = (const float*)d_in[16];
    const float* b5     = (const float*)d_in[17];

    char* ws = (char*)d_ws;
    uint8_t* codes = (uint8_t*)ws;  ws += (size_t)16 << 20;
    char* ping = ws;                ws += 18874368;   // XT(6.29MB) + XR(12.58MB)
    char* pong = ws;                ws += 18874368;
    float* h0  = (float*)ws;        ws += 103168;
    float* hA  = (float*)ws;        ws += 128000;
    float* hB  = (float*)ws;        ws += 128000;

    uint16_t* XTp = (uint16_t*)ping; float* XRp = (float*)(ping + 6291456);
    uint16_t* XTq = (uint16_t*)pong; float* XRq = (float*)(pong + 6291456);

    hipMemsetAsync(h0, 0, (size_t)NB * LIN_IN * 4, stream);

    prep_kernel<<<2048 + 64, 256, 0, stream>>>(sM, codes, 16 * 1024 * 1024 / 4,
                                               labels, XTq, XRq);

    // stages 1,2: wlc alone (LDS-staged)
    wlc_gemm<<<dim3(16, 2, 16), 256, 0, stream>>>(XTq, XRq, XTp, XRp, codes, K1, 0, 1, 1, 2, 0);
    wlc_gemm<<<dim3(16, 2, 16), 256, 0, stream>>>(XTp, XRp, XTq, XRq, codes, K1, 1, 0, 2, 2, 1);

    // stages 3,4: fused with conv half-strips (960 fine-grain conv blocks each)
    fused_wlc_conv<<<960 + 1024, 256, 0, stream>>>(
        960, 0, sM, cw1, cb1, cw2, cb2, h0,
        XTq, XRq, XTp, XRp, codes, K2, 0, 1, 2, 4, 0);
    fused_wlc_conv<<<960 + 1024, 256, 0, stream>>>(
        960, 960, sM, cw1, cb1, cw2, cb2, h0,
        XTp, XRp, XTq, XRq, codes, K2, 1, 0, 4, 4, 1);

    spp_kernel<<<64, 1024, 0, stream>>>(XRq, h0);

    fc_kernel<2><<<500, 256, 0, stream>>>(h0, W1, b1, hA, LIN_IN, 2000, 1);
    fc_kernel<4><<<500, 256, 0, stream>>>(hA, W2, b2, hB, 2000, 2000, 1);
    fc_kernel<4><<<500, 256, 0, stream>>>(hB, W3, b3, hA, 2000, 2000, 1);
    fc_kernel<4><<<500, 256, 0, stream>>>(hA, W4, b4, hB, 2000, 2000, 1);
    fc_kernel<4><<<1,   256, 0, stream>>>(hB, W5, b5, (float*)d_out, 2000, 2, 0);
}

// Round 17
// 313.016 us; speedup vs baseline: 1.0641x; 1.0641x over previous
//
#include <hip/hip_runtime.h>
#include <stdint.h>

#define NN 1024
#define FF 35
#define LIN_IN 1610
#define NB 16

typedef short short8 __attribute__((ext_vector_type(8)));
typedef float f32x4 __attribute__((ext_vector_type(4)));
typedef float f32x2 __attribute__((ext_vector_type(2)));

__device__ __forceinline__ float leakyf(float x) { return fmaxf(x, 0.01f * x); }
__device__ __forceinline__ uint16_t to_bf16(float v) {
    return (uint16_t)((__float_as_uint(v) + 0x8000u) >> 16);
}
__device__ __forceinline__ f32x2 sp2(float s) { return (f32x2){s, s}; }
__device__ __forceinline__ f32x2 leaky2(f32x2 v) {
    f32x2 r;
    r.x = fmaxf(v.x, 0.01f * v.x);
    r.y = fmaxf(v.y, 0.01f * v.y);
    return r;
}
// orderable-uint mapping for float max via integer atomicMax (no NaNs in data)
__device__ __forceinline__ uint32_t mapf(float x) {
    uint32_t u = __float_as_uint(x);
    return (u & 0x80000000u) ? ~u : (u | 0x80000000u);
}
__device__ __forceinline__ float unmapf(uint32_t u) {
    return (u & 0x80000000u) ? __uint_as_float(u & 0x7FFFFFFFu) : __uint_as_float(~u);
}

// ---------------------------------------------------------------- prep: codes (s->u8) + labels->XT0/XR0 in one launch
__global__ __launch_bounds__(256)
void prep_kernel(const float* __restrict__ s, uint8_t* __restrict__ codes, int n4,
                 const float* __restrict__ labels, uint16_t* __restrict__ XT0,
                 float* __restrict__ XR0)
{
    const int bid = blockIdx.x;
    if (bid < 2048) {
        int i = bid * 256 + threadIdx.x;
        for (; i < n4; i += 2048 * 256) {
            float4 v = ((const float4*)s)[i];
            uchar4 c;
            c.x = (uint8_t)v.x; c.y = (uint8_t)v.y; c.z = (uint8_t)v.z; c.w = (uint8_t)v.w;
            ((uchar4*)codes)[i] = c;
        }
    } else {
        __shared__ float buf[256 * FF];
        const int lb = bid - 2048;
        const int si = lb >> 2;
        const int i0 = (lb & 3) * 256;
        const float* src = labels + ((size_t)si * NN + i0) * FF;
        for (int t = threadIdx.x; t < 256 * FF; t += 256) buf[t] = src[t];
        __syncthreads();
        for (int f = 0; f < 48; ++f) {
            const int ii = threadIdx.x;
            float v = (f < FF) ? buf[ii * FF + f] : 0.f;
            size_t o = ((size_t)si * 48 + f) * 1024 + i0 + ii;
            XR0[o] = v;
            XT0[o] = to_bf16(v);
        }
    }
}

// ---------------------------------------------------------------- one-hot A-fragment expansion
__device__ __forceinline__ short8 expand_onehot(uint2 cd, uint32_t dupK) {
    union { uint32_t u[4]; short8 v; } r;
#pragma unroll
    for (int h = 0; h < 2; ++h) {
        uint32_t d = h ? cd.y : cd.x;
        uint32_t y = d ^ dupK;
        uint32_t m = (~(((y & 0x7F7F7F7Fu) + 0x7F7F7F7Fu) | y)) & 0x80808080u;
        uint32_t m2 = m >> 7;                               // 0x01 at matched bytes
        r.u[h * 2 + 0] = ((m2 & 0xFFu) | ((m2 & 0xFF00u) << 8)) * 0x3F80u;
        r.u[h * 2 + 1] = (((m2 >> 16) & 0xFFu) | ((m2 >> 8) & 0xFF0000u)) * 0x3F80u;
    }
    return r.v;
}

// ---------------------------------------------------------------- WLC step body, LDS-staged both operands (r15 proven)
__device__ __forceinline__
void wlc_body(int mt, int nt, int s,
              const uint16_t* __restrict__ XT_in, const float* __restrict__ XR_in,
              uint16_t* __restrict__ XT_out, float* __restrict__ XR_out,
              const uint8_t* __restrict__ codes, const float* __restrict__ Kg,
              int t, int shift, int nch_in, int nch_out, int do_leaky)
{
    __shared__ __align__(16) uint16_t xs[48 * 64];   // B tile, XOR swizzle
    __shared__ __align__(16) uint8_t  cds[64 * 80];  // codes tile, 80B row stride

    const int tid   = threadIdx.x;
    const int wid   = tid >> 6;
    const int lane  = tid & 63;
    const int chout = nt;
    const int inch  = chout >> shift;
    const int kch   = chout & 1;
    const int i0    = mt * 64;
    const int irow0 = i0 + wid * 16;

    // B staging: 48 rows x 64 bf16 = 384 16B-units
    const int u0 = tid, u1 = tid + 256;
    const bool v1 = (u1 < 384);
    const int r0s = u0 >> 3, c80 = u0 & 7;
    const int r1s = u1 >> 3, c81 = u1 & 7;
    const uint16_t* src0 = XT_in + (((size_t)s * nch_in + inch) * 48 + r0s) * 1024 + c80 * 8;
    const uint16_t* src1 = XT_in + (((size_t)s * nch_in + inch) * 48 + (v1 ? r1s : 0)) * 1024 + c81 * 8;
    uint16_t* dst0 = &xs[r0s * 64 + ((c80 ^ (r0s & 7)) * 8)];
    uint16_t* dst1 = &xs[(v1 ? r1s : 0) * 64 + ((c81 ^ (r1s & 7)) * 8)];

    // codes staging: 64 rows x 64 B; thread t -> row t>>2, bytes (t&3)*16
    const int crow = tid >> 2, ccol = (tid & 3) * 16;
    const uint8_t* csrc = codes + ((size_t)s << 20) + (size_t)(i0 + crow) * 1024 + ccol;
    uint8_t* cdst = &cds[crow * 80 + ccol];

    const int cd_off = (wid * 16 + (lane & 15)) * 80 + ((lane >> 4) << 3);

    f32x4 acc[4][3];
#pragma unroll
    for (int k = 0; k < 4; ++k)
#pragma unroll
        for (int nf = 0; nf < 3; ++nf) acc[k][nf] = (f32x4){0.f, 0.f, 0.f, 0.f};

    uint4 preB0 = *(const uint4*)src0;
    uint4 preB1 = v1 ? *(const uint4*)src1 : (uint4){0, 0, 0, 0};
    uint4 preC  = *(const uint4*)csrc;

    for (int jt = 0; jt < 16; ++jt) {
        __syncthreads();                  // prev tile's LDS reads done
        *(uint4*)dst0 = preB0;
        if (v1) *(uint4*)dst1 = preB1;
        *(uint4*)cdst = preC;
        __syncthreads();

        if (jt < 15) {                    // prefetch next tile during compute
            const int j1 = (jt + 1) * 64;
            preB0 = *(const uint4*)(src0 + j1);
            if (v1) preB1 = *(const uint4*)(src1 + j1);
            preC  = *(const uint4*)(csrc + j1);
        }

        const uint2 cd0 = *(const uint2*)&cds[cd_off];
        const uint2 cd1 = *(const uint2*)&cds[cd_off + 32];

        short8 bfr[3][2];
#pragma unroll
        for (int nf = 0; nf < 3; ++nf)
#pragma unroll
            for (int kk = 0; kk < 2; ++kk) {
                int n = nf * 16 + (lane & 15);
                int c8 = kk * 4 + (lane >> 4);
                bfr[nf][kk] = *(const short8*)&xs[n * 64 + ((c8 ^ (n & 7)) * 8)];
            }

#pragma unroll
        for (int k = 0; k < 4; ++k) {
            const uint32_t dupK = 0x01010101u * (k + 1);
#pragma unroll
            for (int kk = 0; kk < 2; ++kk) {
                short8 af = expand_onehot(kk ? cd1 : cd0, dupK);
#pragma unroll
                for (int nf = 0; nf < 3; ++nf)
                    acc[k][nf] = __builtin_amdgcn_mfma_f32_16x16x32_bf16(
                        af, bfr[nf][kk], acc[k][nf], 0, 0, 0);
            }
        }
    }

    float sc[4][3];
#pragma unroll
    for (int nf = 0; nf < 3; ++nf) {
        int fnl = nf * 16 + (lane & 15);
#pragma unroll
        for (int k = 0; k < 4; ++k)
            sc[k][nf] = (fnl < FF) ? Kg[((kch * 2 + t) * 4 + k) * FF + fnl] : 0.f;
    }

#pragma unroll
    for (int nf = 0; nf < 3; ++nf) {
        int fnl = nf * 16 + (lane & 15);
        int irow = irow0 + ((lane >> 4) << 2);
        f32x4 rr = sc[0][nf] * acc[0][nf];
        rr += sc[1][nf] * acc[1][nf];
        rr += sc[2][nf] * acc[2][nf];
        rr += sc[3][nf] * acc[3][nf];
        size_t rb = (((size_t)s * nch_in + inch) * 48 + fnl) * 1024 + irow;
        float4 rd = *(const float4*)&XR_in[rb];
        float y0 = rr.x + rd.x, y1 = rr.y + rd.y, y2 = rr.z + rd.z, y3 = rr.w + rd.w;
        if (do_leaky) { y0 = leakyf(y0); y1 = leakyf(y1); y2 = leakyf(y2); y3 = leakyf(y3); }
        size_t ob = (((size_t)s * nch_out + chout) * 48 + fnl) * 1024 + irow;
        *(float4*)&XR_out[ob] = make_float4(y0, y1, y2, y3);
        ushort4 bv;
        bv.x = to_bf16(y0); bv.y = to_bf16(y1); bv.z = to_bf16(y2); bv.w = to_bf16(y3);
        *(ushort4*)&XT_out[ob] = bv;
    }
}

__global__ __launch_bounds__(256, 2)
void wlc_gemm(const uint16_t* __restrict__ XT_in, const float* __restrict__ XR_in,
              uint16_t* __restrict__ XT_out, float* __restrict__ XR_out,
              const uint8_t* __restrict__ codes, const float* __restrict__ Kg,
              int t, int shift, int nch_in, int nch_out, int do_leaky)
{
    wlc_body(blockIdx.x, blockIdx.y, blockIdx.z, XT_in, XR_in, XT_out, XR_out,
             codes, Kg, t, shift, nch_in, nch_out, do_leaky);
}

// ---------------------------------------------------------------- conv body: r15 full-strip form, but reads CODES (u8)
// sM's values are integers 0..4 — identical to codes. Reading u8 cuts conv's
// memory footprint 4x (33->8 MB/launch) and makes conv share wlc's codes
// working set in L2 (same data). u8->f32 via v_cvt_f32_ubyte (1 VALU each).
__device__ __forceinline__
void conv_body(int ss, int simg,
               const uint8_t* __restrict__ codes,
               const float* __restrict__ cw1, const float* __restrict__ cb1,
               const float* __restrict__ cw2, const float* __restrict__ cb2,
               float* __restrict__ h0)
{
    __shared__ float bins[30];
    const int tid  = threadIdx.x;
    const int lane = tid & 63;
    const int r0   = ss * 17;
    const int rb2  = ss / 30;
    const int rb3  = ss / 20;

    if (tid < 30) bins[tid] = 0.f;
    __syncthreads();

    const int colbase = (tid < 255) ? tid * 4 : 254 * 4;
    const uint8_t* cp = codes + ((size_t)simg << 20) + colbase;

    f32x2 w1p[9], w2p[45], b1p;
#pragma unroll
    for (int i = 0; i < 9; ++i) { w1p[i].x = cw1[i]; w1p[i].y = cw1[9 + i]; }
#pragma unroll
    for (int o = 0; o < 5; ++o)
#pragma unroll
        for (int i = 0; i < 9; ++i) {
            w2p[o * 9 + i].x = cw2[(o * 2 + 0) * 9 + i];
            w2p[o * 9 + i].y = cw2[(o * 2 + 1) * 9 + i];
        }
    b1p.x = cb1[0]; b1p.y = cb1[1];
    float b2r[5];
#pragma unroll
    for (int i = 0; i < 5; ++i) b2r[i] = cb2[i];

    float sw[3][8];
    f32x2 z1w[3][6];
    float acc[5][4];
#pragma unroll
    for (int o = 0; o < 5; ++o)
#pragma unroll
        for (int j = 0; j < 4; ++j) acc[o][j] = 0.f;

#define LOADROW(slot, rabs) do { \
    uint32_t b0 = *(const uint32_t*)(cp + (size_t)(rabs) * 1024); \
    uint32_t b1 = *(const uint32_t*)(cp + (size_t)(rabs) * 1024 + 4); \
    sw[slot][0] = (float)(b0 & 0xFFu);        sw[slot][1] = (float)((b0 >> 8) & 0xFFu); \
    sw[slot][2] = (float)((b0 >> 16) & 0xFFu); sw[slot][3] = (float)(b0 >> 24); \
    sw[slot][4] = (float)(b1 & 0xFFu);        sw[slot][5] = (float)((b1 >> 8) & 0xFFu); \
    sw[slot][6] = (float)((b1 >> 16) & 0xFFu); sw[slot][7] = (float)(b1 >> 24); } while(0)

#define Z1ROW(P) do { \
    _Pragma("unroll") for (int jj = 0; jj < 6; ++jj) { \
        f32x2 a = b1p; \
        _Pragma("unroll") for (int dc = 0; dc < 3; ++dc) { \
            a += sp2(sw[((P)+2)%3][jj+dc]) * w1p[0+dc]; \
            a += sp2(sw[(P)%3    ][jj+dc]) * w1p[3+dc]; \
            a += sp2(sw[((P)+1)%3][jj+dc]) * w1p[6+dc]; } \
        z1w[((P)+2)%3][jj] = leaky2(a); } } while(0)

#define Z2ROW(P) do { \
    _Pragma("unroll") for (int o = 0; o < 5; ++o) { \
      _Pragma("unroll") for (int j = 0; j < 4; ++j) { \
        f32x2 a = (f32x2){b2r[o], 0.f}; \
        _Pragma("unroll") for (int dc = 0; dc < 3; ++dc) { \
            a += z1w[(P)%3    ][j+dc] * w2p[o*9+0+dc]; \
            a += z1w[((P)+1)%3][j+dc] * w2p[o*9+3+dc]; \
            a += z1w[((P)+2)%3][j+dc] * w2p[o*9+6+dc]; } \
        float sres = a.x + a.y; \
        acc[o][j] += fmaxf(sres, 0.01f * sres); } } } while(0)

    LOADROW(0, r0 + 0);
    LOADROW(1, r0 + 1);
    LOADROW(2, r0 + 2);
    Z1ROW(1);
    LOADROW(0, r0 + 3);
    Z1ROW(2);

#pragma unroll 1
    for (int rr = 0; rr < 15; rr += 3) {
        LOADROW(1, r0 + rr + 4); Z1ROW(0); Z2ROW(0);
        LOADROW(2, r0 + rr + 5); Z1ROW(1); Z2ROW(1);
        LOADROW(0, r0 + rr + 6); Z1ROW(2); Z2ROW(2);
    }
    LOADROW(1, r0 + 19); Z1ROW(0); Z2ROW(0);
    LOADROW(2, r0 + 20); Z1ROW(1); Z2ROW(1);

#undef LOADROW
#undef Z1ROW
#undef Z2ROW

    if (tid == 255) {
#pragma unroll
        for (int o = 0; o < 5; ++o)
#pragma unroll
            for (int j = 0; j < 4; ++j) acc[o][j] = 0.f;
    }

    int cb2c[4], cb3c[4];
#pragma unroll
    for (int j = 0; j < 4; ++j) {
        int col = colbase + j;
        int a2 = col / 510; if (a2 > 1) a2 = 1;
        int a3 = col / 340; if (a3 > 2) a3 = 2;
        cb2c[j] = a2; cb3c[j] = a3;
    }

#pragma unroll
    for (int o = 0; o < 5; ++o) {
        float t1 = acc[o][0] + acc[o][1] + acc[o][2] + acc[o][3];
        float pa = 0.f, pb = 0.f, q0 = 0.f, q1 = 0.f, q2 = 0.f;
#pragma unroll
        for (int j = 0; j < 4; ++j) {
            float v = acc[o][j];
            if (cb2c[j] == 0) pa += v; else pb += v;
            if (cb3c[j] == 0) q0 += v; else if (cb3c[j] == 1) q1 += v; else q2 += v;
        }
#pragma unroll
        for (int d = 32; d >= 1; d >>= 1) {
            t1 += __shfl_xor(t1, d, 64);
            pa += __shfl_xor(pa, d, 64);
            pb += __shfl_xor(pb, d, 64);
            q0 += __shfl_xor(q0, d, 64);
            q1 += __shfl_xor(q1, d, 64);
            q2 += __shfl_xor(q2, d, 64);
        }
        if (lane == 0) {
            atomicAdd(&bins[o * 6 + 0], t1);
            atomicAdd(&bins[o * 6 + 1], pa);
            atomicAdd(&bins[o * 6 + 2], pb);
            atomicAdd(&bins[o * 6 + 3], q0);
            atomicAdd(&bins[o * 6 + 4], q1);
            atomicAdd(&bins[o * 6 + 5], q2);
        }
    }
    __syncthreads();
    if (tid < 30) {
        int o = tid / 6, b = tid % 6;
        int off; float scale;
        if (b == 0)      { off = 0;                         scale = 1.f / (1020.f * 1020.f); }
        else if (b <= 2) { off = 1 + rb2 * 2 + (b - 1);     scale = 1.f / (510.f * 510.f); }
        else             { off = 5 + rb3 * 3 + (b - 3);     scale = 1.f / (340.f * 340.f); }
        atomicAdd(h0 + (size_t)simg * LIN_IN + 1540 + o * 14 + off, bins[tid] * scale);
    }
}

// ---------------------------------------------------------------- fused: conv strips + wlc stage blocks
__global__ __launch_bounds__(256, 2)
void fused_wlc_conv(int convBlocks, int imgBase,
                    const float* __restrict__ cw1, const float* __restrict__ cb1,
                    const float* __restrict__ cw2, const float* __restrict__ cb2,
                    float* __restrict__ h0,
                    const uint16_t* __restrict__ XT_in, const float* __restrict__ XR_in,
                    uint16_t* __restrict__ XT_out, float* __restrict__ XR_out,
                    const uint8_t* __restrict__ codes, const float* __restrict__ Kg,
                    int t, int shift, int nch_in, int nch_out, int do_leaky)
{
    const int bid = blockIdx.x;
    if (bid < convBlocks) {
        conv_body(bid % 60, imgBase + bid / 60, codes, cw1, cb1, cw2, cb2, h0);
    } else {
        const int w = bid - convBlocks;
        wlc_body(w & 15, (w >> 4) & 3, w >> 6, XT_in, XR_in, XT_out, XR_out,
                 codes, Kg, t, shift, nch_in, nch_out, do_leaky);
    }
}

// ---------------------------------------------------------------- spp max: one block per (img,ch), scatter + inline unmap
__global__ __launch_bounds__(1024)
void spp_kernel(const float* __restrict__ xr4, float* __restrict__ h0)
{
    constexpr int KH[10] = {1024, 512, 342, 256, 205, 171, 147, 128, 114, 103};
    constexpr int PH[10] = {0, 0, 2, 0, 1, 2, 5, 0, 2, 6};
    constexpr int KW[10] = {35, 18, 12, 9, 7, 6, 5, 5, 4, 4};
    constexpr int PW[10] = {0, 1, 1, 1, 0, 1, 0, 2, 1, 2};
    constexpr int OW[10] = {1, 2, 3, 4, 5, 6, 7, 7, 9, 9};
    constexpr int OHW[10] = {1, 4, 9, 16, 25, 36, 49, 56, 81, 90};
    constexpr int BASE[10] = {0, 1, 5, 14, 30, 55, 91, 140, 204, 285};

    __shared__ uint32_t cells[385];
    const int c = blockIdx.x & 3;
    const int s = blockIdx.x >> 2;
    const int r = threadIdx.x;           // one row per thread

    if (r < 385) cells[r] = 0u;
    __syncthreads();

    const float* bp = xr4 + ((size_t)s * 4 + c) * (48 * 1024) + r;

    int addr[10];
#pragma unroll
    for (int pi = 0; pi < 10; ++pi)
        addr[pi] = BASE[pi] + ((r + PH[pi]) / KH[pi]) * OW[pi];

    float acc[10];
#pragma unroll
    for (int pi = 0; pi < 10; ++pi) acc[pi] = -3.402823466e38f;

#pragma unroll
    for (int f = 0; f < FF; ++f) {
        const float v = bp[(size_t)f * 1024];
#pragma unroll
        for (int pi = 0; pi < 10; ++pi) {
            const int cbin = (f + PW[pi]) / KW[pi];                    // compile-time
            const int cbn  = (f + 1 < FF) ? ((f + 1 + PW[pi]) / KW[pi]) : -1;
            if (cbin < OW[pi]) {
                acc[pi] = fmaxf(acc[pi], v);
                if (cbn != cbin) {                                     // static flush site
                    atomicMax(&cells[addr[pi] + cbin], mapf(acc[pi]));
                    acc[pi] = -3.402823466e38f;
                }
            }
        }
    }

    __syncthreads();
    if (r < 385) {
        int p1 = 1, base = 0;
        while (p1 < 10 && r >= base + p1 * p1) { base += p1 * p1; ++p1; }
        const int ci = r - base;
        const float val = (ci < OHW[p1 - 1]) ? unmapf(cells[r]) : 0.f;
        h0[(size_t)s * LIN_IN + c * 385 + r] = val;
    }
}

// ---------------------------------------------------------------- FC: 1 output/wave, vectorized unguarded main + tail
template<int VEC>
__global__ __launch_bounds__(256)
void fc_kernel(const float* __restrict__ in, const float* __restrict__ W,
               const float* __restrict__ bias, float* __restrict__ out,
               int K, int Nout, int do_leaky)
{
    const int o = (blockIdx.x * 256 + threadIdx.x) >> 6;
    const int lane = threadIdx.x & 63;
    if (o >= Nout) return;
    const float* wrow = W + (size_t)o * K;
    float acc[16];
#pragma unroll
    for (int b = 0; b < 16; ++b) acc[b] = 0.f;

    const int step = 64 * VEC;
    const int kmain = (K / step) * step;
#pragma unroll 2
    for (int k0 = 0; k0 < kmain; k0 += step) {
        const int kk = k0 + lane * VEC;
        if (VEC == 4) {
            float4 w = *(const float4*)(wrow + kk);
#pragma unroll
            for (int b = 0; b < 16; ++b) {
                float4 h = *(const float4*)(in + (size_t)b * K + kk);
                acc[b] += w.x * h.x + w.y * h.y + w.z * h.z + w.w * h.w;
            }
        } else {
            float2 w = *(const float2*)(wrow + kk);
#pragma unroll
            for (int b = 0; b < 16; ++b) {
                float2 h = *(const float2*)(in + (size_t)b * K + kk);
                acc[b] += w.x * h.x + w.y * h.y;
            }
        }
    }
    {
        const int kk = kmain + lane * VEC;
        if (kk < K) {
            if (VEC == 4) {
                float4 w = *(const float4*)(wrow + kk);
#pragma unroll
                for (int b = 0; b < 16; ++b) {
                    float4 h = *(const float4*)(in + (size_t)b * K + kk);
                    acc[b] += w.x * h.x + w.y * h.y + w.z * h.z + w.w * h.w;
                }
            } else {
                float2 w = *(const float2*)(wrow + kk);
#pragma unroll
                for (int b = 0; b < 16; ++b) {
                    float2 h = *(const float2*)(in + (size_t)b * K + kk);
                    acc[b] += w.x * h.x + w.y * h.y;
                }
            }
        }
    }

    float res = 0.f;
#pragma unroll
    for (int b = 0; b < 16; ++b) {
        float v = acc[b];
#pragma unroll
        for (int od = 32; od >= 1; od >>= 1) v += __shfl_xor(v, od, 64);
        if (lane == b) res = v;
    }
    if (lane < 16) {
        const float y = res + bias[o];
        out[(size_t)lane * Nout + o] = do_leaky ? leakyf(y) : y;
    }
}

// ---------------------------------------------------------------- launch
extern "C" void kernel_launch(void* const* d_in, const int* in_sizes, int n_in,
                              void* d_out, int out_size, void* d_ws, size_t ws_size,
                              hipStream_t stream)
{
    const float* labels = (const float*)d_in[0];
    const float* sM     = (const float*)d_in[1];
    const float* K1     = (const float*)d_in[2];
    const float* K2     = (const float*)d_in[3];
    const float* cw1    = (const float*)d_in[4];
    const float* cb1    = (const float*)d_in[5];
    const float* cw2    = (const float*)d_in[6];
    const float* cb2    = (const float*)d_in[7];
    const float* W1     = (const float*)d_in[8];
    const float* b1     = (const float*)d_in[9];
    const float* W2     = (const float*)d_in[10];
    const float* b2     = (const float*)d_in[11];
    const float* W3     = (const float*)d_in[12];
    const float* b3     = (const float*)d_in[13];
    const float* W4     = (const float*)d_in[14];
    const float* b4     = (const float*)d_in[15];
    const float* W5     = (const float*)d_in[16];
    const float* b5     = (const float*)d_in[17];

    char* ws = (char*)d_ws;
    uint8_t* codes = (uint8_t*)ws;  ws += (size_t)16 << 20;
    char* ping = ws;                ws += 18874368;   // XT(6.29MB) + XR(12.58MB)
    char* pong = ws;                ws += 18874368;
    float* h0  = (float*)ws;        ws += 103168;
    float* hA  = (float*)ws;        ws += 128000;
    float* hB  = (float*)ws;        ws += 128000;

    uint16_t* XTp = (uint16_t*)ping; float* XRp = (float*)(ping + 6291456);
    uint16_t* XTq = (uint16_t*)pong; float* XRq = (float*)(pong + 6291456);

    hipMemsetAsync(h0, 0, (size_t)NB * LIN_IN * 4, stream);

    prep_kernel<<<2048 + 64, 256, 0, stream>>>(sM, codes, 16 * 1024 * 1024 / 4,
                                               labels, XTq, XRq);

    // stages 1,2: wlc alone (LDS-staged)
    wlc_gemm<<<dim3(16, 2, 16), 256, 0, stream>>>(XTq, XRq, XTp, XRp, codes, K1, 0, 1, 1, 2, 0);
    wlc_gemm<<<dim3(16, 2, 16), 256, 0, stream>>>(XTp, XRp, XTq, XRq, codes, K1, 1, 0, 2, 2, 1);

    // stages 3,4: fused with conv halves (conv reads codes u8 - shares wlc's L2 set)
    fused_wlc_conv<<<480 + 1024, 256, 0, stream>>>(
        480, 0, cw1, cb1, cw2, cb2, h0,
        XTq, XRq, XTp, XRp, codes, K2, 0, 1, 2, 4, 0);
    fused_wlc_conv<<<480 + 1024, 256, 0, stream>>>(
        480, 8, cw1, cb1, cw2, cb2, h0,
        XTp, XRp, XTq, XRq, codes, K2, 1, 0, 4, 4, 1);

    spp_kernel<<<64, 1024, 0, stream>>>(XRq, h0);

    fc_kernel<2><<<500, 256, 0, stream>>>(h0, W1, b1, hA, LIN_IN, 2000, 1);
    fc_kernel<4><<<500, 256, 0, stream>>>(hA, W2, b2, hB, 2000, 2000, 1);
    fc_kernel<4><<<500, 256, 0, stream>>>(hB, W3, b3, hA, 2000, 2000, 1);
    fc_kernel<4><<<500, 256, 0, stream>>>(hA, W4, b4, hB, 2000, 2000, 1);
    fc_kernel<4><<<1,   256, 0, stream>>>(hB, W5, b5, (float*)d_out, 2000, 2, 0);
}